// Round 1
// baseline (773.915 us; speedup 1.0000x reference)
//
#include <hip/hip_runtime.h>
#include <math.h>

namespace {
constexpr int KNB  = 7;                  // neighbor volumes
constexpr int PS   = 7;                  // patch size
constexpr int CCH  = 3;                  // image channels
constexpr int IH   = 256;
constexpr int IW   = 256;
constexpr int PADR = 3;                  // PS/2
constexpr int QN   = IH * IW;            // 65536
constexpr int ON   = 32;                 // candidates per query
constexpr int EN   = 64;                 // embedding dim
constexpr int FN   = CCH * PS * PS;      // 147
constexpr int KC   = KNB * CCH;          // 21 output channels per map
}

// One 64-lane wave per query; 4 queries per 256-thread block.
__global__ __launch_bounds__(256) void n3_query_kernel(
    const float* __restrict__ x,        // [N, F]
    const float* __restrict__ xe,       // [N, E]
    const float* __restrict__ ye,       // [Q, E]
    const float* __restrict__ log_temp, // [H, W]
    const int*   __restrict__ cand,     // [Q, O]
    const int*   __restrict__ qindex,   // [Q]
    float*       __restrict__ vid)      // [KC, H, W] (pre-zeroed)
{
    const int wib  = threadIdx.x >> 6;
    const int lane = threadIdx.x & 63;
    const int q    = (blockIdx.x << 2) + wib;

    __shared__ float w_lds[4][ON][8];   // padded to 8 for aligned vector reads
    __shared__ int   c_lds[4][ON];

    const int qpix = qindex[q];
    const int qi = qpix / IW;
    const int qj = qpix % IW;

    // ---- lt: mean over the 7x7 zero-padded log_temp patch (divide by 49 always) ----
    float ltv = 0.f;
    if (lane < PS * PS) {
        int pi = lane / PS, pj = lane % PS;
        int yy = qi + pi - PADR, xx = qj + pj - PADR;
        if (yy >= 0 && yy < IH && xx >= 0 && xx < IW)
            ltv = log_temp[yy * IW + xx];
    }
    #pragma unroll
    for (int s = 32; s >= 1; s >>= 1) ltv += __shfl_xor(ltv, s);
    const float itemp = expf(-ltv * (1.f / 49.f));   // 1 / exp(lt)

    // ---- search: lanes 0..31 each own one candidate ----
    float d2 = 0.f;
    if (lane < ON) {
        const int cidx = cand[q * ON + lane];
        c_lds[wib][lane] = cidx;
        const float4* xr = (const float4*)(xe + (size_t)cidx * EN);
        const float4* yr = (const float4*)(ye + (size_t)q * EN);
        float dot = 0.f, xn = 0.f, yn = 0.f;
        #pragma unroll
        for (int e = 0; e < EN / 4; ++e) {
            float4 a = xr[e];
            float4 b = yr[e];
            dot += a.x * b.x + a.y * b.y + a.z * b.z + a.w * b.w;
            xn  += a.x * a.x + a.y * a.y + a.z * a.z + a.w * a.w;
            yn  += b.x * b.x + b.y * b.y + b.z * b.z + b.w * b.w;
        }
        d2 = yn + xn - 2.f * dot;
    }

    // ---- NNN weights: 7 rounds of softmax over the 32-lane group ----
    float logit = -d2 * itemp;
    float wk[KNB];
    #pragma unroll
    for (int k = 0; k < KNB; ++k) {
        float m = logit;
        #pragma unroll
        for (int s = 16; s >= 1; s >>= 1) m = fmaxf(m, __shfl_xor(m, s));
        float ev = expf(logit - m);
        float ssum = ev;
        #pragma unroll
        for (int s = 16; s >= 1; s >>= 1) ssum += __shfl_xor(ssum, s);
        float w = ev / ssum;
        wk[k] = w;
        logit += logf(fmaxf(1.f - w, 1e-6f));
    }
    if (lane < ON) {
        #pragma unroll
        for (int k = 0; k < KNB; ++k) w_lds[wib][lane][k] = wk[k];
    }
    __syncthreads();

    // ---- wpsum over F=147 (3 chunks of 64 lanes) + atomic fold ----
    for (int it = 0; it < 3; ++it) {
        const int f = it * 64 + lane;
        const bool act = f < FN;
        float acc[KNB];
        #pragma unroll
        for (int k = 0; k < KNB; ++k) acc[k] = 0.f;
        #pragma unroll 8
        for (int o = 0; o < ON; ++o) {
            const int cidx = c_lds[wib][o];
            const float xv = act ? x[(size_t)cidx * FN + f] : 0.f;
            #pragma unroll
            for (int k = 0; k < KNB; ++k) acc[k] += xv * w_lds[wib][o][k];
        }
        if (act) {
            const int c  = f / (PS * PS);
            const int r  = f - c * (PS * PS);
            const int pi = r / PS;
            const int pj = r - pi * PS;
            const int yy = qi + pi - PADR;
            const int xx = qj + pj - PADR;
            if (yy >= 0 && yy < IH && xx >= 0 && xx < IW) {
                #pragma unroll
                for (int k = 0; k < KNB; ++k)
                    atomicAdd(&vid[(((size_t)(k * CCH + c)) * IH + yy) * IW + xx], acc[k]);
            }
        }
    }
}

// wvid = fold(ones) with qindex = arange(H*W): separable border counts.
__global__ __launch_bounds__(256) void wvid_kernel(float* __restrict__ wvid) {
    int idx = blockIdx.x * blockDim.x + threadIdx.x;
    if (idx >= QN) return;
    int y  = idx / IW;
    int xx = idx - y * IW;
    int cy = min(PS - 1, y  + PADR) - max(0, y  - (IH - 1 - PADR)) + 1;
    int cx = min(PS - 1, xx + PADR) - max(0, xx - (IW - 1 - PADR)) + 1;
    float v = (float)(cy * cx);
    #pragma unroll
    for (int ch = 0; ch < KC; ++ch) wvid[(size_t)ch * QN + idx] = v;
}

extern "C" void kernel_launch(void* const* d_in, const int* in_sizes, int n_in,
                              void* d_out, int out_size, void* d_ws, size_t ws_size,
                              hipStream_t stream) {
    const float* x    = (const float*)d_in[0];
    const float* xe   = (const float*)d_in[1];
    const float* ye   = (const float*)d_in[2];
    const float* ltm  = (const float*)d_in[3];
    const int*   cand = (const int*)d_in[4];
    const int*   qidx = (const int*)d_in[5];

    float* vid  = (float*)d_out;
    float* wvid = vid + (size_t)KC * QN;

    // vid is accumulated with atomics -> must be zeroed every launch
    hipMemsetAsync(vid, 0, (size_t)KC * QN * sizeof(float), stream);

    n3_query_kernel<<<QN / 4, 256, 0, stream>>>(x, xe, ye, ltm, cand, qidx, vid);
    wvid_kernel<<<(QN + 255) / 256, 256, 0, stream>>>(wvid);
}

// Round 2
// 611.411 us; speedup vs baseline: 1.2658x; 1.2658x over previous
//
#include <hip/hip_runtime.h>
#include <math.h>

namespace {
constexpr int KNB  = 7;                  // neighbor volumes
constexpr int PS   = 7;                  // patch size
constexpr int CCH  = 3;                  // image channels
constexpr int IH   = 256;
constexpr int IW   = 256;
constexpr int PADR = 3;                  // PS/2
constexpr int QN   = IH * IW;            // 65536
constexpr int ON   = 32;                 // candidates per query
constexpr int EN   = 64;                 // embedding dim
constexpr int FN   = CCH * PS * PS;      // 147
constexpr int KC   = KNB * CCH;          // 21 output channels per map
constexpr int TQ   = 8;                  // tile = TQ x TQ queries per block
constexpr int CH   = TQ + PS - 1;        // 14: LDS canvas side
constexpr int CELEM = KC * CH * CH;      // 4116 canvas floats
}

// One block = 8x8 query tile, 4 waves; each wave serially handles 16 queries.
// Fold accumulates into an LDS canvas; one atomic flush per block at the end.
__global__ __launch_bounds__(256) void n3_tile_kernel(
    const float* __restrict__ x,        // [N, F]
    const float* __restrict__ xe,       // [N, E]
    const float* __restrict__ ye,       // [Q, E]
    const float* __restrict__ log_temp, // [H, W]
    const int*   __restrict__ cand,     // [Q, O]
    const int*   __restrict__ qindex,   // [Q]
    float*       __restrict__ vid)      // [KC, H, W] (pre-zeroed)
{
    __shared__ float canvas[CELEM];     // [KC][CH][CH]
    __shared__ float w_lds[4][ON][8];   // per-wave weights, padded row
    __shared__ int   c_lds[4][ON];      // per-wave candidate indices

    const int wib  = threadIdx.x >> 6;
    const int lane = threadIdx.x & 63;
    const int by   = blockIdx.x / (IW / TQ);
    const int bx   = blockIdx.x - by * (IW / TQ);
    const int y0   = by * TQ;
    const int x0   = bx * TQ;

    for (int i = threadIdx.x; i < CELEM; i += 256) canvas[i] = 0.f;
    __syncthreads();

    for (int t = wib; t < TQ * TQ; t += 4) {
        const int ty = t >> 3;
        const int tx = t & 7;
        const int q  = (y0 + ty) * IW + (x0 + tx);

        const int qpix = qindex[q];
        const int qi = qpix / IW;
        const int qj = qpix - qi * IW;

        // ---- lt: mean over zero-padded 7x7 log_temp patch ----
        float ltv = 0.f;
        if (lane < PS * PS) {
            int pi = lane / PS, pj = lane % PS;
            int yy = qi + pi - PADR, xx = qj + pj - PADR;
            if (yy >= 0 && yy < IH && xx >= 0 && xx < IW)
                ltv = log_temp[yy * IW + xx];
        }
        #pragma unroll
        for (int s = 32; s >= 1; s >>= 1) ltv += __shfl_xor(ltv, s);
        const float itemp = expf(-ltv * (1.f / 49.f));   // 1/exp(lt)

        // ---- search: lanes 0..31 own one candidate each ----
        float d2 = 0.f;
        if (lane < ON) {
            const int cidx = cand[q * ON + lane];
            c_lds[wib][lane] = cidx;
            const float4* xr = (const float4*)(xe + (size_t)cidx * EN);
            const float4* yr = (const float4*)(ye + (size_t)q * EN);
            float dot = 0.f, xn = 0.f, yn = 0.f;
            #pragma unroll
            for (int e = 0; e < EN / 4; ++e) {
                float4 a = xr[e];
                float4 b = yr[e];
                dot += a.x * b.x + a.y * b.y + a.z * b.z + a.w * b.w;
                xn  += a.x * a.x + a.y * a.y + a.z * a.z + a.w * a.w;
                yn  += b.x * b.x + b.y * b.y + b.z * b.z + b.w * b.w;
            }
            d2 = yn + xn - 2.f * dot;
        }

        // ---- NNN weights: 7 iterated softmaxes over the 32-lane group ----
        float logit = -d2 * itemp;
        float wk[KNB];
        #pragma unroll
        for (int k = 0; k < KNB; ++k) {
            float m = logit;
            #pragma unroll
            for (int s = 16; s >= 1; s >>= 1) m = fmaxf(m, __shfl_xor(m, s));
            float ev = expf(logit - m);
            float ssum = ev;
            #pragma unroll
            for (int s = 16; s >= 1; s >>= 1) ssum += __shfl_xor(ssum, s);
            float w = ev / ssum;
            wk[k] = w;
            logit += logf(fmaxf(1.f - w, 1e-6f));
        }
        if (lane < ON) {
            #pragma unroll
            for (int k = 0; k < KNB; ++k) w_lds[wib][lane][k] = wk[k];
        }
        // wave-private LDS buffers: no __syncthreads needed

        // ---- wpsum over F=147 (3 chunks of 64 lanes) + LDS fold ----
        #pragma unroll
        for (int it = 0; it < 3; ++it) {
            const int f = it * 64 + lane;
            const bool act = f < FN;
            float acc[KNB];
            #pragma unroll
            for (int k = 0; k < KNB; ++k) acc[k] = 0.f;
            #pragma unroll 8
            for (int o = 0; o < ON; ++o) {
                const int cidx = c_lds[wib][o];
                const float xv = act ? x[(size_t)cidx * FN + f] : 0.f;
                #pragma unroll
                for (int k = 0; k < KNB; ++k) acc[k] += xv * w_lds[wib][o][k];
            }
            if (act) {
                const int c  = f / (PS * PS);
                const int r  = f - c * (PS * PS);
                const int pi = r / PS;
                const int pj = r - pi * PS;
                // canvas covers image rows [y0-3, y0+10]; local = qi + pi - y0
                const int ly = qi + pi - y0;
                const int lx = qj + pj - x0;
                #pragma unroll
                for (int k = 0; k < KNB; ++k)
                    atomicAdd(&canvas[(k * CCH + c) * (CH * CH) + ly * CH + lx], acc[k]);
            }
        }
    }

    __syncthreads();

    // ---- flush canvas to global with crop bounds-check ----
    for (int i = threadIdx.x; i < CELEM; i += 256) {
        const float v = canvas[i];
        if (v != 0.f) {
            const int ch  = i / (CH * CH);
            const int rem = i - ch * (CH * CH);
            const int ly  = rem / CH;
            const int lx  = rem - ly * CH;
            const int gy  = y0 - PADR + ly;
            const int gx  = x0 - PADR + lx;
            if (gy >= 0 && gy < IH && gx >= 0 && gx < IW)
                atomicAdd(&vid[(size_t)ch * QN + gy * IW + gx], v);
        }
    }
}

// wvid = fold(ones) with qindex = arange(H*W): separable border counts.
__global__ __launch_bounds__(256) void wvid_kernel(float* __restrict__ wvid) {
    int idx = blockIdx.x * blockDim.x + threadIdx.x;
    if (idx >= QN) return;
    int y  = idx / IW;
    int xx = idx - y * IW;
    int cy = min(PS - 1, y  + PADR) - max(0, y  - (IH - 1 - PADR)) + 1;
    int cx = min(PS - 1, xx + PADR) - max(0, xx - (IW - 1 - PADR)) + 1;
    float v = (float)(cy * cx);
    #pragma unroll
    for (int ch = 0; ch < KC; ++ch) wvid[(size_t)ch * QN + idx] = v;
}

extern "C" void kernel_launch(void* const* d_in, const int* in_sizes, int n_in,
                              void* d_out, int out_size, void* d_ws, size_t ws_size,
                              hipStream_t stream) {
    const float* x    = (const float*)d_in[0];
    const float* xe   = (const float*)d_in[1];
    const float* ye   = (const float*)d_in[2];
    const float* ltm  = (const float*)d_in[3];
    const int*   cand = (const int*)d_in[4];
    const int*   qidx = (const int*)d_in[5];

    float* vid  = (float*)d_out;
    float* wvid = vid + (size_t)KC * QN;

    // vid is accumulated with atomics -> must be zeroed every launch
    hipMemsetAsync(vid, 0, (size_t)KC * QN * sizeof(float), stream);

    n3_tile_kernel<<<(IH / TQ) * (IW / TQ), 256, 0, stream>>>(x, xe, ye, ltm, cand, qidx, vid);
    wvid_kernel<<<(QN + 255) / 256, 256, 0, stream>>>(wvid);
}